// Round 1
// baseline (262.435 us; speedup 1.0000x reference)
//
#include <hip/hip_runtime.h>

#define E_EDGES   1000000
#define NNODES    2048
#define DLAT      64
#define HCH       128
#define KP        168            // LDS / ws row stride in bf16 elements (pad: 2-way bank alias = free)
#define TILE      64
#define NTILES    (E_EDGES / TILE)   // 15625 exact
#define NSPREAD   8
#define GRID_GEMM 2048
#define ZVEC      (32 * 2048 * 64 / 4)   // 1048576 float4s
#define ZBLK      512

typedef short  shortx8 __attribute__((ext_vector_type(8)));
typedef float  floatx4 __attribute__((ext_vector_type(4)));

__device__ __forceinline__ unsigned short f2bf(float f) {
  union { float f; unsigned int u; } v; v.f = f;
  unsigned int r = (v.u + 0x7fffu + ((v.u >> 16) & 1u)) >> 16;
  return (unsigned short)r;
}

// ---------------------------------------------------------------- prep ----
__global__ void k_prep(const float* __restrict__ z, const float* __restrict__ W1,
                       const float* __restrict__ b1,
                       unsigned short* __restrict__ zb, unsigned short* __restrict__ w1t,
                       float* __restrict__ gstats) {
  int bid = blockIdx.x;
  if (bid < ZBLK) {
    const float4* z4 = (const float4*)z;
    ushort4* zb4 = (ushort4*)zb;
    for (int i = bid * 256 + threadIdx.x; i < ZVEC; i += ZBLK * 256) {
      float4 v = z4[i];
      ushort4 o;
      o.x = f2bf(v.x); o.y = f2bf(v.y); o.z = f2bf(v.z); o.w = f2bf(v.w);
      zb4[i] = o;
    }
  } else if (bid == ZBLK) {
    // W1T[n][k] = W1[k][n] for k<132, b1[n] at k=132, 0 for k in 133..167
    for (int idx = threadIdx.x; idx < 132 * HCH; idx += 256) {
      int k = idx >> 7, n = idx & 127;              // coalesced read of W1
      w1t[n * KP + k] = f2bf(W1[idx]);
    }
    for (int idx = threadIdx.x; idx < HCH * (KP - 132); idx += 256) {
      int n = idx / (KP - 132);
      int k = 132 + (idx - n * (KP - 132));
      w1t[n * KP + k] = (k == 132) ? f2bf(b1[n]) : (unsigned short)0;
    }
  } else {
    for (int i = threadIdx.x; i < NSPREAD * 2 * HCH; i += 256) gstats[i] = 0.f;
  }
}

// ---------------------------------------------------------------- gemm ----
// Per block: 64-edge tile x 128 channels, K padded to 160 (5 MFMA k-steps).
// 4 waves in 2x2: wave=(eh,nh) covers edges eh*32..+31, channels nh*64..+63.
// B fragments (W1T) live in registers for the whole kernel.
template<bool OUT>
__global__ __launch_bounds__(256, 2)
void k_gemm(const unsigned short* __restrict__ zb,
            const unsigned short* __restrict__ w1t,
            const int* __restrict__ ei,
            const float* __restrict__ attr,
            float* __restrict__ gstats,
            const float* __restrict__ ab,
            const float* __restrict__ W2,
            const float* __restrict__ b2,
            float* __restrict__ out) {
  __shared__ __align__(16) unsigned short A[TILE * KP];   // 21504 B
  __shared__ int rows[TILE * 2];
  __shared__ float s_sum[HCH], s_sq[HCH];
  __shared__ float po[TILE];

  const int tid  = threadIdx.x;
  const int lane = tid & 63;
  const int wave = tid >> 6;
  const int l15  = lane & 15;
  const int quad = lane >> 4;
  const int eh   = wave >> 1;
  const int nh   = wave & 1;

  // ---- B fragments in registers: b[nt][kk], n = nh*64 + nt*16 + l15
  shortx8 bfr[4][5];
#pragma unroll
  for (int nt = 0; nt < 4; ++nt) {
    const unsigned short* bp = w1t + (nh * 64 + nt * 16 + l15) * KP + quad * 8;
#pragma unroll
    for (int kk = 0; kk < 5; ++kk)
      bfr[nt][kk] = *(const shortx8*)(bp + kk * 32);
  }

  float ea[4], ebb[4], ew2[4], b2v = 0.f;
  float ssum[4] = {0.f, 0.f, 0.f, 0.f}, ssq[4] = {0.f, 0.f, 0.f, 0.f};
  if (OUT) {
#pragma unroll
    for (int nt = 0; nt < 4; ++nt) {
      int c = nh * 64 + nt * 16 + l15;
      ea[nt]  = ab[c];
      ebb[nt] = ab[HCH + c];
      ew2[nt] = W2[c];
    }
    b2v = b2[0];
  } else {
    if (tid < HCH) { s_sum[tid] = 0.f; s_sq[tid] = 0.f; }
  }

  for (int tile = blockIdx.x; tile < NTILES; tile += gridDim.x) {
    const int e0 = tile * TILE;
    __syncthreads();                       // protect A/rows/po from prev iter
    if (tid < TILE) {
      int s = ei[e0 + tid];
      int d = ei[E_EDGES + e0 + tid];
      rows[tid * 2]     = s;                                   // src_idx == src
      rows[tid * 2 + 1] = (s & ~(NNODES - 1)) | (d & (NNODES - 1)); // src batch!
    }
    __syncthreads();
    {
      const int e = tid >> 2, q = tid & 3;
      const int r = rows[e * 2 + (q >> 1)];
      const uint4* src = (const uint4*)(zb + r * DLAT + (q & 1) * 32);
      uint4* dst = (uint4*)(A + e * KP + q * 32);
      dst[0] = src[0]; dst[1] = src[1]; dst[2] = src[2]; dst[3] = src[3];
    }
    if (tid < 64) {
      float4 av = ((const float4*)attr)[e0 + tid];
      ushort4 a0; a0.x = f2bf(av.x); a0.y = f2bf(av.y); a0.z = f2bf(av.z); a0.w = f2bf(av.w);
      *(ushort4*)(A + tid * KP + 128) = a0;
      ushort4 a1; a1.x = f2bf(1.0f); a1.y = 0; a1.z = 0; a1.w = 0;  // bias lane
      *(ushort4*)(A + tid * KP + 132) = a1;
    } else if (tid < 128) {
      int e = tid - 64;
      uint4 zed = {0, 0, 0, 0};
      *(uint4*)(A + e * KP + 136) = zed;
      *(uint4*)(A + e * KP + 144) = zed;
    } else if (tid < 192) {
      int e = tid - 128;
      uint4 zed = {0, 0, 0, 0};
      *(uint4*)(A + e * KP + 152) = zed;
      *(uint4*)(A + e * KP + 160) = zed;
    }
    __syncthreads();

    floatx4 acc[2][4];
#pragma unroll
    for (int mt = 0; mt < 2; ++mt)
#pragma unroll
      for (int nt = 0; nt < 4; ++nt)
        acc[mt][nt] = (floatx4){0.f, 0.f, 0.f, 0.f};

#pragma unroll
    for (int kk = 0; kk < 5; ++kk) {
      shortx8 afr[2];
#pragma unroll
      for (int mt = 0; mt < 2; ++mt)
        afr[mt] = *(const shortx8*)(A + (eh * 32 + mt * 16 + l15) * KP + kk * 32 + quad * 8);
#pragma unroll
      for (int mt = 0; mt < 2; ++mt)
#pragma unroll
        for (int nt = 0; nt < 4; ++nt)
          acc[mt][nt] = __builtin_amdgcn_mfma_f32_16x16x32_bf16(
              afr[mt], bfr[nt][kk], acc[mt][nt], 0, 0, 0);
    }

    if (!OUT) {
      // C/D layout: col = lane&15 (channel), row = quad*4 + reg (edge)
#pragma unroll
      for (int nt = 0; nt < 4; ++nt) {
        float s = 0.f, q = 0.f;
#pragma unroll
        for (int mt = 0; mt < 2; ++mt)
#pragma unroll
          for (int r = 0; r < 4; ++r) {
            float h = acc[mt][nt][r];
            s += h; q += h * h;
          }
        ssum[nt] += s; ssq[nt] += q;
      }
    } else {
      float tpart[2][4];
#pragma unroll
      for (int mt = 0; mt < 2; ++mt)
#pragma unroll
        for (int r = 0; r < 4; ++r) {
          float t = 0.f;
#pragma unroll
          for (int nt = 0; nt < 4; ++nt) {
            float h = acc[mt][nt][r];
            float p = ea[nt] * h + ebb[nt];
            p = (p >= 0.f) ? p : 0.2f * p;
            t += p * ew2[nt];
          }
          t += __shfl_xor(t, 1);
          t += __shfl_xor(t, 2);
          t += __shfl_xor(t, 4);
          t += __shfl_xor(t, 8);   // now t = sum over this wave's 64 channels
          tpart[mt][r] = t;
        }
      // combine the two channel-halves (nh=0/1 waves share the same edges)
      if (nh == 1 && l15 == 0) {
#pragma unroll
        for (int mt = 0; mt < 2; ++mt)
#pragma unroll
          for (int r = 0; r < 4; ++r)
            po[eh * 32 + mt * 16 + quad * 4 + r] = tpart[mt][r];
      }
      __syncthreads();
      if (nh == 0 && l15 == 0) {
#pragma unroll
        for (int mt = 0; mt < 2; ++mt)
#pragma unroll
          for (int r = 0; r < 4; ++r) {
            int el = eh * 32 + mt * 16 + quad * 4 + r;
            out[e0 + el] = tpart[mt][r] + po[el] + b2v;
          }
      }
    }
  }

  if (!OUT) {
#pragma unroll
    for (int nt = 0; nt < 4; ++nt) {
      float s = ssum[nt], q = ssq[nt];
      s += __shfl_xor(s, 16); s += __shfl_xor(s, 32);
      q += __shfl_xor(q, 16); q += __shfl_xor(q, 32);
      if (quad == 0) {
        atomicAdd(&s_sum[nh * 64 + nt * 16 + l15], s);
        atomicAdd(&s_sq [nh * 64 + nt * 16 + l15], q);
      }
    }
    __syncthreads();
    float* dstc = gstats + (blockIdx.x & (NSPREAD - 1)) * 2 * HCH;
    if (tid < HCH)          atomicAdd(&dstc[tid], s_sum[tid]);
    else if (tid < 2 * HCH) atomicAdd(&dstc[tid], s_sq[tid - HCH]);
  }
}

// --------------------------------------------------------------- final ----
__global__ void k_final(const float* __restrict__ gstats,
                        const float* __restrict__ gamma,
                        const float* __restrict__ beta,
                        float* __restrict__ ab) {
  int c = threadIdx.x;
  if (c < HCH) {
    float S = 0.f, Q = 0.f;
    for (int i = 0; i < NSPREAD; ++i) {
      S += gstats[i * 2 * HCH + c];
      Q += gstats[i * 2 * HCH + HCH + c];
    }
    float inv = 1.0f / (float)E_EDGES;
    float mu = S * inv;
    float var = Q * inv - mu * mu;
    float rstd = rsqrtf(var + 1e-5f);
    float a = gamma[c] * rstd;
    ab[c] = a;
    ab[HCH + c] = beta[c] - mu * a;
  }
}

// -------------------------------------------------------------- launch ----
extern "C" void kernel_launch(void* const* d_in, const int* in_sizes, int n_in,
                              void* d_out, int out_size, void* d_ws, size_t ws_size,
                              hipStream_t stream) {
  const float* z     = (const float*)d_in[0];
  const float* attr  = (const float*)d_in[1];
  const float* W1    = (const float*)d_in[2];
  const float* b1    = (const float*)d_in[3];
  const float* gamma = (const float*)d_in[4];
  const float* beta  = (const float*)d_in[5];
  const float* W2    = (const float*)d_in[6];
  const float* b2    = (const float*)d_in[7];
  const int*   ei    = (const int*)d_in[8];
  float* out = (float*)d_out;

  char* ws = (char*)d_ws;
  unsigned short* zb  = (unsigned short*)ws;                 // 8,388,608 B
  unsigned short* w1t = (unsigned short*)(ws + 8388608);     //    43,008 B
  float* gstats       = (float*)(ws + 8431616);              //     8,192 B
  float* ab           = (float*)(ws + 8439808);              //     1,024 B

  k_prep<<<ZBLK + 2, 256, 0, stream>>>(z, W1, b1, zb, w1t, gstats);
  k_gemm<false><<<GRID_GEMM, 256, 0, stream>>>(zb, w1t, ei, attr, gstats,
                                               nullptr, W2, b2, nullptr);
  k_final<<<1, 128, 0, stream>>>(gstats, gamma, beta, ab);
  k_gemm<true><<<GRID_GEMM, 256, 0, stream>>>(zb, w1t, ei, attr, gstats,
                                              ab, W2, b2, out);
}